// Round 4
// baseline (248.926 us; speedup 1.0000x reference)
//
#include <hip/hip_runtime.h>
#include <math.h>

// AutoregressiveFlowLayer MI355X — round 4.
// R3 post-mortem: 95us typical; LDS pipe ~40us, VALU ~38us, MFMA ~18us — none
// saturated => ~40% barrier/dependency idle (5 barriers x 16 tiles, 2 blocks/CU).
// R4: (1) ALL weight B-frags loaded direct global->registers (coalesced 64B runs,
// LLC-resident) — removes LDS weight scratch, its 4-way scatter conflicts, and all
// preamble barriers; (2) LDS 59->43KB => 3 blocks/CU (__launch_bounds__(256,3)),
// grid 1024 x 8 tiles; (3) epilogue(t) merged with gather(t+1) (regA vs regB +
// double-buffered xgf) => 4 barriers/tile.
// Error model (R2/R3 data): extra absmax ~ 0.125 * (neglected-term/2^-16) => 3-term
// split is mandatory; 2-term would be ~30 absmax. Keep 3-term.

#define RR 32
#define DD 1024
#define HH 128
#define OO 64
#define TROWS 32
#define TILES_PER_BLOCK 8
#define BLOCKS_PER_R 32

#define SH  132   // packed h row stride (dwords): stores 2-addr/bank (free), reads ~opt
#define SXP 36    // packed xg row stride (dwords)
#define XS  36    // xgf f32 row stride
#define OS  68    // outb f32 row stride

typedef short bf16x8_t __attribute__((ext_vector_type(8)));
typedef float f32x4_t __attribute__((ext_vector_type(4)));
typedef unsigned short u16;
typedef unsigned int u32;

__device__ __forceinline__ u16 bf16_rne(float x) {
    u32 u = __float_as_uint(x);
    u += 0x7FFFu + ((u >> 16) & 1u);
    return (u16)(u >> 16);
}
__device__ __forceinline__ float bf16_tof(u16 h) {
    return __uint_as_float(((u32)h) << 16);
}
__device__ __forceinline__ u32 pack_split(float v) {
    u16 h = bf16_rne(v);
    u16 l = bf16_rne(v - bf16_tof(h));
    return (u32)h | ((u32)l << 16);
}
// 8 packed dwords -> hi frag (8 bf16) + lo frag
__device__ __forceinline__ void unpack8(const u32* p, bf16x8_t& hi, bf16x8_t& lo) {
    uint4 a = *reinterpret_cast<const uint4*>(p);
    uint4 b = *reinterpret_cast<const uint4*>(p + 4);
    union { u32 u[4]; bf16x8_t v; } H, L;
    H.u[0] = __builtin_amdgcn_perm(a.y, a.x, 0x05040100u);
    H.u[1] = __builtin_amdgcn_perm(a.w, a.z, 0x05040100u);
    H.u[2] = __builtin_amdgcn_perm(b.y, b.x, 0x05040100u);
    H.u[3] = __builtin_amdgcn_perm(b.w, b.z, 0x05040100u);
    L.u[0] = __builtin_amdgcn_perm(a.y, a.x, 0x07060302u);
    L.u[1] = __builtin_amdgcn_perm(a.w, a.z, 0x07060302u);
    L.u[2] = __builtin_amdgcn_perm(b.y, b.x, 0x07060302u);
    L.u[3] = __builtin_amdgcn_perm(b.w, b.z, 0x07060302u);
    hi = H.v; lo = L.v;
}
__device__ __forceinline__ f32x4_t mfma16(bf16x8_t a, bf16x8_t b, f32x4_t c) {
    return __builtin_amdgcn_mfma_f32_16x16x32_bf16(a, b, c, 0, 0, 0);
}
// Direct global -> register B-frag (masked, split hi/lo). W layout [k][col] row-major.
// Frag element j: (k = k0+j, col). Lanes of one q-group are 16 consecutive cols -> 64B runs.
__device__ __forceinline__ void load_bfrag(const float* __restrict__ W,
                                           const int* __restrict__ M,
                                           int ldc, int col, int k0,
                                           bf16x8_t& fh, bf16x8_t& fl)
{
    union { u16 u[8]; bf16x8_t v; } H, L;
#pragma unroll
    for (int j = 0; j < 8; ++j) {
        const int o = (k0 + j) * ldc + col;
        const float e = M[o] ? W[o] : 0.f;
        const u16 h = bf16_rne(e);
        H.u[j] = h;
        L.u[j] = bf16_rne(e - bf16_tof(h));
    }
    fh = H.v; fl = L.v;
}

__global__ __launch_bounds__(256, 3)
void made_flow_r4(const float* __restrict__ inputs,
                  const float* __restrict__ W1,
                  const float* __restrict__ W2,
                  const float* __restrict__ Wout,
                  const int* __restrict__ idx,
                  const int* __restrict__ valid,
                  const int* __restrict__ M1,
                  const int* __restrict__ M2,
                  const int* __restrict__ Mout,
                  float* __restrict__ out)
{
    // regA: h1 packed (32 x SH dwords)  UNION  outb f32 (32 x OS)
    // regB: h2 packed                    UNION  xg packed
    __shared__ __align__(16) char regA[TROWS * SH * 4];   // 16.9 KB
    __shared__ __align__(16) char regB[TROWS * SH * 4];   // 16.9 KB
    __shared__ __align__(16) float xgf[2][TROWS * XS];    // 9.2 KB (double-buffered)
    __shared__ int   idx_s[RR];
    __shared__ float v_s[RR];

    u32*   const h1p  = (u32*)regA;
    float* const outb = (float*)regA;
    u32*   const h2p  = (u32*)regB;
    u32*   const xgp  = (u32*)regB;

    const int tid  = threadIdx.x;
    const int r    = blockIdx.x / BLOCKS_PER_R;
    const int rb   = blockIdx.x % BLOCKS_PER_R;
    const int lane = tid & 63;
    const int wave = tid >> 6;
    const int q    = lane >> 4;
    const int l16  = lane & 15;
    const int nb   = 2 * wave;

    if (tid < RR) {
        idx_s[tid] = idx[r * RR + tid];
        v_s[tid]   = valid[r * RR + tid] ? 1.f : 0.f;
    }

    // ---- all weight B-frags: direct global -> registers (no LDS, no barriers) ----
    bf16x8_t b1h[2], b1l[2];        // W1: K=32,  this wave's cols 16*(nb+ni)+l16
    bf16x8_t b2h[2][4], b2l[2][4];  // W2: K=128 (ks*32+q*8)
    bf16x8_t boh[4],    bol[4];     // Wout: K=128, cols 16*wave+l16
    {
        const float* W1r = W1 + r * RR * HH;   const int* M1r = M1 + r * RR * HH;
        const float* W2r = W2 + r * HH * HH;   const int* M2r = M2 + r * HH * HH;
        const float* Wor = Wout + r * HH * OO; const int* Mor = Mout + r * HH * OO;
#pragma unroll
        for (int ni = 0; ni < 2; ++ni)
            load_bfrag(W1r, M1r, HH, 16 * (nb + ni) + l16, q * 8, b1h[ni], b1l[ni]);
#pragma unroll
        for (int ni = 0; ni < 2; ++ni)
#pragma unroll
            for (int ks = 0; ks < 4; ++ks)
                load_bfrag(W2r, M2r, HH, 16 * (nb + ni) + l16, ks * 32 + q * 8,
                           b2h[ni][ks], b2l[ni][ks]);
#pragma unroll
        for (int ks = 0; ks < 4; ++ks)
            load_bfrag(Wor, Mor, OO, 16 * wave + l16, ks * 32 + q * 8, boh[ks], bol[ks]);
    }
    __syncthreads();   // idx_s/v_s visible

    const f32x4_t zero4 = {0.f, 0.f, 0.f, 0.f};

    // ---- prologue gather for tile 0 ----
    {
        const int row  = tid >> 3;
        const int g    = tid & 7;
        const int base = (rb * TILES_PER_BLOCK * TROWS + row) * DD;
        uint4 px; float4 fx;
        float x0 = inputs[base + idx_s[4 * g + 0]] * v_s[4 * g + 0];
        float x1 = inputs[base + idx_s[4 * g + 1]] * v_s[4 * g + 1];
        float x2 = inputs[base + idx_s[4 * g + 2]] * v_s[4 * g + 2];
        float x3 = inputs[base + idx_s[4 * g + 3]] * v_s[4 * g + 3];
        px.x = pack_split(x0); px.y = pack_split(x1);
        px.z = pack_split(x2); px.w = pack_split(x3);
        fx.x = x0; fx.y = x1; fx.z = x2; fx.w = x3;
        *(uint4*)&xgp[row * SXP + 4 * g]    = px;
        *(float4*)&xgf[0][row * XS + 4 * g] = fx;
    }
    __syncthreads();

    for (int t = 0; t < TILES_PER_BLOCK; ++t) {
        const int row0 = (rb * TILES_PER_BLOCK + t) * TROWS;

        // ---- phase 1: h1 = relu(xg @ W1m)  M=32 N=128 K=32 ----
        {
            bf16x8_t ah[2], al[2];
#pragma unroll
            for (int mi = 0; mi < 2; ++mi)
                unpack8(&xgp[(16 * mi + l16) * SXP + q * 8], ah[mi], al[mi]);
            f32x4_t acc[2][2];
#pragma unroll
            for (int ni = 0; ni < 2; ++ni)
#pragma unroll
                for (int mi = 0; mi < 2; ++mi) {
                    f32x4_t a = zero4;
                    a = mfma16(ah[mi], b1h[ni], a);
                    a = mfma16(al[mi], b1h[ni], a);
                    a = mfma16(ah[mi], b1l[ni], a);
                    acc[mi][ni] = a;
                }
#pragma unroll
            for (int mi = 0; mi < 2; ++mi)
#pragma unroll
                for (int ni = 0; ni < 2; ++ni)
#pragma unroll
                    for (int i = 0; i < 4; ++i)
                        h1p[(16 * mi + 4 * q + i) * SH + 16 * (nb + ni) + l16] =
                            pack_split(fmaxf(acc[mi][ni][i], 0.f));
        }
        __syncthreads();

        // ---- phase 2: h2 = relu(h1 @ W2m)  K=128, B in registers ----
        {
            f32x4_t acc[2][2] = {{zero4, zero4}, {zero4, zero4}};
#pragma unroll
            for (int ks = 0; ks < 4; ++ks) {
#pragma unroll
                for (int mi = 0; mi < 2; ++mi) {
                    bf16x8_t ah, al;
                    unpack8(&h1p[(16 * mi + l16) * SH + ks * 32 + q * 8], ah, al);
#pragma unroll
                    for (int ni = 0; ni < 2; ++ni) {
                        f32x4_t a = acc[mi][ni];
                        a = mfma16(ah, b2h[ni][ks], a);
                        a = mfma16(al, b2h[ni][ks], a);
                        a = mfma16(ah, b2l[ni][ks], a);
                        acc[mi][ni] = a;
                    }
                }
            }
#pragma unroll
            for (int mi = 0; mi < 2; ++mi)
#pragma unroll
                for (int ni = 0; ni < 2; ++ni)
#pragma unroll
                    for (int i = 0; i < 4; ++i)
                        h2p[(16 * mi + 4 * q + i) * SH + 16 * (nb + ni) + l16] =
                            pack_split(fmaxf(acc[mi][ni][i], 0.f));
        }
        __syncthreads();

        // ---- phase 3: outb = h2 @ Woutm  N=64, B in registers ----
        {
            f32x4_t acc[2] = {zero4, zero4};
#pragma unroll
            for (int ks = 0; ks < 4; ++ks) {
#pragma unroll
                for (int mi = 0; mi < 2; ++mi) {
                    bf16x8_t ah, al;
                    unpack8(&h2p[(16 * mi + l16) * SH + ks * 32 + q * 8], ah, al);
                    f32x4_t a = acc[mi];
                    a = mfma16(ah, boh[ks], a);
                    a = mfma16(al, boh[ks], a);
                    a = mfma16(ah, bol[ks], a);
                    acc[mi] = a;
                }
            }
#pragma unroll
            for (int mi = 0; mi < 2; ++mi)
#pragma unroll
                for (int i = 0; i < 4; ++i)
                    outb[(16 * mi + 4 * q + i) * OS + 16 * wave + l16] = acc[mi][i];
        }
        __syncthreads();

        // ---- epilogue(t) + gather(t+1): disjoint LDS regions, one barrier ----
        {
            const int row = tid >> 3;
            const int g   = tid & 7;
            float4 o0 = *(const float4*)&outb[row * OS + 8 * g];
            float4 o1 = *(const float4*)&outb[row * OS + 8 * g + 4];
            float4 xv = *(const float4*)&xgf[t & 1][row * XS + 4 * g];
            float p;
            {
                float u0 = (xv.x - o0.x) * __expf(-o0.y);
                float u1 = (xv.y - o0.z) * __expf(-o0.w);
                float u2 = (xv.z - o1.x) * __expf(-o1.y);
                float u3 = (xv.w - o1.z) * __expf(-o1.w);
                p  = (-0.5f * u0 * u0 - 0.91893853320467266954f - o0.y) * v_s[4 * g + 0];
                p += (-0.5f * u1 * u1 - 0.91893853320467266954f - o0.w) * v_s[4 * g + 1];
                p += (-0.5f * u2 * u2 - 0.91893853320467266954f - o1.y) * v_s[4 * g + 2];
                p += (-0.5f * u3 * u3 - 0.91893853320467266954f - o1.w) * v_s[4 * g + 3];
            }
            p += __shfl_xor(p, 1);
            p += __shfl_xor(p, 2);
            p += __shfl_xor(p, 4);
            if (g == 0) out[(row0 + row) * RR + r] = p;

            if (t + 1 < TILES_PER_BLOCK) {
                const int base = (row0 + TROWS + row) * DD;
                uint4 px; float4 fx;
                float x0 = inputs[base + idx_s[4 * g + 0]] * v_s[4 * g + 0];
                float x1 = inputs[base + idx_s[4 * g + 1]] * v_s[4 * g + 1];
                float x2 = inputs[base + idx_s[4 * g + 2]] * v_s[4 * g + 2];
                float x3 = inputs[base + idx_s[4 * g + 3]] * v_s[4 * g + 3];
                px.x = pack_split(x0); px.y = pack_split(x1);
                px.z = pack_split(x2); px.w = pack_split(x3);
                fx.x = x0; fx.y = x1; fx.z = x2; fx.w = x3;
                *(uint4*)&xgp[row * SXP + 4 * g] = px;   // regB: h2p dead after phase-3 reads
                *(float4*)&xgf[(t + 1) & 1][row * XS + 4 * g] = fx;
            }
        }
        __syncthreads();
    }
}

extern "C" void kernel_launch(void* const* d_in, const int* in_sizes, int n_in,
                              void* d_out, int out_size, void* d_ws, size_t ws_size,
                              hipStream_t stream)
{
    const float* inputs = (const float*)d_in[0];
    const float* W1     = (const float*)d_in[1];
    const float* W2     = (const float*)d_in[2];
    const float* Wout   = (const float*)d_in[3];
    const int*   idx    = (const int*)d_in[4];
    const int*   valid  = (const int*)d_in[5];
    const int*   M1     = (const int*)d_in[6];
    const int*   M2     = (const int*)d_in[7];
    const int*   Mout   = (const int*)d_in[8];
    float*       out    = (float*)d_out;

    hipLaunchKernelGGL(made_flow_r4, dim3(RR * BLOCKS_PER_R), dim3(256), 0, stream,
                       inputs, W1, W2, Wout, idx, valid, M1, M2, Mout, out);
}

// Round 5
// 160.901 us; speedup vs baseline: 1.5471x; 1.5471x over previous
//
#include <hip/hip_runtime.h>
#include <math.h>

// AutoregressiveFlowLayer MI355X — round 5.
// R4 post-mortem: direct global->register weight frags SPILLED (WRITE_SIZE 91MB,
// VGPR 84) — compiler only parks persistent frags in AGPRs when they are produced
// by ds_read (R3 evidence: VGPR 96, no spill). => weights MUST stage through LDS
// scratch. Register budget (96 frag + ~90 working) caps us at 2 waves/SIMD; don't
// chase 3 blocks/CU.
// R5 = R3 staging + structural cuts:
//  (1) preamble stages weights as packed (hi|lo<<16) dwords via in-register 4x4
//      transpose + uint4 LDS writes -> conflict-free (was u16 scatter, 8-way).
//  (2) phase-3 accs stay in REGISTERS: shfl_xor(1) pairs shift/log_s, in-wave
//      butterfly reduces over j, tiny red[32][4] cross-wave buffer.
//      -> outb + separate epilogue gone; 3 barriers/tile (was 5).
//  (3) xgf gone (x rebuilt from packed xgp: 2 ops).
//  (4) xgp double-buffered: gather(t+1) runs inside P2, no extra barrier.
//  (5) W1 packed in LDS (read per tile), saves 16 persistent regs.

#define RR 32
#define DD 1024
#define HH 128
#define OO 64
#define TROWS 32
#define TILES_PER_BLOCK 16
#define BLOCKS_PER_R 16

#define SH  132   // packed h row stride (dwords)
#define SXP 36    // packed xg row stride (dwords)
#define SW1 36    // packed W1 [col][k] stride (dwords)
#define SSC 132   // scratch stride (dwords)

typedef short bf16x8_t __attribute__((ext_vector_type(8)));
typedef float f32x4_t __attribute__((ext_vector_type(4)));
typedef unsigned short u16;
typedef unsigned int u32;

__device__ __forceinline__ u16 bf16_rne(float x) {
    u32 u = __float_as_uint(x);
    u += 0x7FFFu + ((u >> 16) & 1u);
    return (u16)(u >> 16);
}
__device__ __forceinline__ float bf16_tof(u16 h) {
    return __uint_as_float(((u32)h) << 16);
}
__device__ __forceinline__ u32 pack_split(float v) {
    u16 h = bf16_rne(v);
    u16 l = bf16_rne(v - bf16_tof(h));
    return (u32)h | ((u32)l << 16);
}
// packed dword: hi in bits 0..15, lo-correction in bits 16..31
__device__ __forceinline__ float unsplit(u32 p) {
    return __uint_as_float(p << 16) + __uint_as_float(p & 0xFFFF0000u);
}
// 8 packed dwords -> hi frag + lo frag
__device__ __forceinline__ void unpack8(const u32* p, bf16x8_t& hi, bf16x8_t& lo) {
    uint4 a = *reinterpret_cast<const uint4*>(p);
    uint4 b = *reinterpret_cast<const uint4*>(p + 4);
    union { u32 u[4]; bf16x8_t v; } H, L;
    H.u[0] = __builtin_amdgcn_perm(a.y, a.x, 0x05040100u);
    H.u[1] = __builtin_amdgcn_perm(a.w, a.z, 0x05040100u);
    H.u[2] = __builtin_amdgcn_perm(b.y, b.x, 0x05040100u);
    H.u[3] = __builtin_amdgcn_perm(b.w, b.z, 0x05040100u);
    L.u[0] = __builtin_amdgcn_perm(a.y, a.x, 0x07060302u);
    L.u[1] = __builtin_amdgcn_perm(a.w, a.z, 0x07060302u);
    L.u[2] = __builtin_amdgcn_perm(b.y, b.x, 0x07060302u);
    L.u[3] = __builtin_amdgcn_perm(b.w, b.z, 0x07060302u);
    hi = H.v; lo = L.v;
}
__device__ __forceinline__ f32x4_t mfma16(bf16x8_t a, bf16x8_t b, f32x4_t c) {
    return __builtin_amdgcn_mfma_f32_16x16x32_bf16(a, b, c, 0, 0, 0);
}

// Stage a [K x NC] (row-major, leading dim ldc, col offset c0) weight block into
// packed-dword [col][k] LDS (stride sd), conflict-free:
// thread reads a 4x4 block coalesced (float4 over cols), transposes in regs,
// writes 4 uint4 (4 consecutive k per col).
__device__ __forceinline__ void stage_block(const float* __restrict__ W,
                                            const int* __restrict__ M,
                                            int ldc, int c0, int K, u32* dst, int sd,
                                            int tid)
{
    const int kb = tid >> 3;           // K/4 groups needed; caller guarantees kb < K/4
    const int cb = tid & 7;            // 8 col-groups of 4 => 32 cols
    if (kb * 4 >= K) return;
    const int k0 = kb * 4;
    float e[4][4];
#pragma unroll
    for (int i = 0; i < 4; ++i) {
        const int o = ((k0 + i) * ldc + c0 + 4 * cb) >> 2;
        float4 w = ((const float4*)W)[o];
        int4   m = ((const int4*)M)[o];
        e[i][0] = m.x ? w.x : 0.f; e[i][1] = m.y ? w.y : 0.f;
        e[i][2] = m.z ? w.z : 0.f; e[i][3] = m.w ? w.w : 0.f;
    }
#pragma unroll
    for (int j = 0; j < 4; ++j) {
        uint4 p;
        p.x = pack_split(e[0][j]); p.y = pack_split(e[1][j]);
        p.z = pack_split(e[2][j]); p.w = pack_split(e[3][j]);
        *(uint4*)&dst[(4 * cb + j) * sd + k0] = p;
    }
}

__global__ __launch_bounds__(256, 2)
void made_flow_r5(const float* __restrict__ inputs,
                  const float* __restrict__ W1,
                  const float* __restrict__ W2,
                  const float* __restrict__ Wout,
                  const int* __restrict__ idx,
                  const int* __restrict__ valid,
                  const int* __restrict__ M1,
                  const int* __restrict__ M2,
                  const int* __restrict__ Mout,
                  float* __restrict__ out)
{
    __shared__ __align__(16) u32 regA[TROWS * SH];      // h1 packed | preamble scratch (16.9 KB)
    __shared__ __align__(16) u32 regB[TROWS * SH];      // h2 packed (16.9 KB)
    __shared__ __align__(16) u32 xgp[2][TROWS * SXP];   // packed xg, double-buffered (9.2 KB)
    __shared__ __align__(16) u32 w1p[HH * SW1];         // packed W1 [col][k] (18.4 KB)
    __shared__ float red[TROWS * 4];                    // cross-wave partials (0.5 KB)
    __shared__ int   idx_s[RR];
    __shared__ float v_s[RR];

    u32* const h1p = regA;
    u32* const scr = regA;
    u32* const h2p = regB;

    const int tid  = threadIdx.x;
    const int r    = blockIdx.x / BLOCKS_PER_R;
    const int rb   = blockIdx.x % BLOCKS_PER_R;
    const int lane = tid & 63;
    const int wave = tid >> 6;
    const int q    = lane >> 4;
    const int l16  = lane & 15;
    const int nb   = 2 * wave;

    if (tid < RR) {
        idx_s[tid] = idx[r * RR + tid];
        v_s[tid]   = valid[r * RR + tid] ? 1.f : 0.f;
    }

    // ---- stage W1 -> persistent packed LDS [col][k] ----
    {
        // 128 cols x 32 k: thread: cb=tid&31 (col0=4*cb), kb=tid>>5 (k0=4*kb)
        const float* W1r = W1 + r * RR * HH;
        const int*   M1r = M1 + r * RR * HH;
        const int cb = tid & 31, kb = tid >> 5;
        const int k0 = kb * 4, c0 = cb * 4;
        float e[4][4];
#pragma unroll
        for (int i = 0; i < 4; ++i) {
            const int o = ((k0 + i) * HH + c0) >> 2;
            float4 w = ((const float4*)W1r)[o];
            int4   m = ((const int4*)M1r)[o];
            e[i][0] = m.x ? w.x : 0.f; e[i][1] = m.y ? w.y : 0.f;
            e[i][2] = m.z ? w.z : 0.f; e[i][3] = m.w ? w.w : 0.f;
        }
#pragma unroll
        for (int j = 0; j < 4; ++j) {
            uint4 p;
            p.x = pack_split(e[0][j]); p.y = pack_split(e[1][j]);
            p.z = pack_split(e[2][j]); p.w = pack_split(e[3][j]);
            *(uint4*)&w1p[(c0 + j) * SW1 + k0] = p;
        }
    }

    // ---- stage W2/Wout -> per-wave register frags via LDS scratch (AGPR-friendly) ----
    bf16x8_t b2h[2][4], b2l[2][4];  // W2 cols 16*(nb+ni)+l16
    bf16x8_t boh[4],    bol[4];     // Wout cols 16*wave+l16
    {
        const float* W2r = W2 + r * HH * HH;   const int* M2r = M2 + r * HH * HH;
        const float* Wor = Wout + r * HH * OO; const int* Mor = Mout + r * HH * OO;
        for (int c = 0; c < 4; ++c) {
            __syncthreads();
            stage_block(W2r, M2r, HH, 32 * c, HH, scr, SSC, tid);
            __syncthreads();
            if (wave == c) {
#pragma unroll
                for (int ni = 0; ni < 2; ++ni)
#pragma unroll
                    for (int ks = 0; ks < 4; ++ks)
                        unpack8(&scr[(16 * ni + l16) * SSC + ks * 32 + q * 8],
                                b2h[ni][ks], b2l[ni][ks]);
            }
        }
        for (int c = 0; c < 2; ++c) {
            __syncthreads();
            stage_block(Wor, Mor, OO, 32 * c, HH, scr, SSC, tid);
            __syncthreads();
            if ((wave >> 1) == c) {
                const int nl = wave & 1;
#pragma unroll
                for (int ks = 0; ks < 4; ++ks)
                    unpack8(&scr[(16 * nl + l16) * SSC + ks * 32 + q * 8],
                            boh[ks], bol[ks]);
            }
        }
    }
    __syncthreads();

    // ---- prologue gather -> xgp[0] ----
    {
        const int row  = tid >> 3;
        const int g    = tid & 7;
        const int base = (rb * TILES_PER_BLOCK * TROWS + row) * DD;
        uint4 px;
        px.x = pack_split(inputs[base + idx_s[4 * g + 0]] * v_s[4 * g + 0]);
        px.y = pack_split(inputs[base + idx_s[4 * g + 1]] * v_s[4 * g + 1]);
        px.z = pack_split(inputs[base + idx_s[4 * g + 2]] * v_s[4 * g + 2]);
        px.w = pack_split(inputs[base + idx_s[4 * g + 3]] * v_s[4 * g + 3]);
        *(uint4*)&xgp[0][row * SXP + 4 * g] = px;
    }
    __syncthreads();

    const f32x4_t zero4 = {0.f, 0.f, 0.f, 0.f};

    for (int t = 0; t < TILES_PER_BLOCK; ++t) {
        const int row0 = (rb * TILES_PER_BLOCK + t) * TROWS;
        const u32* xcur = xgp[t & 1];

        // ---- phase 1: h1 = relu(xg @ W1m)  M=32 N=128 K=32 (B from packed LDS) ----
        {
            bf16x8_t ah[2], al[2];
#pragma unroll
            for (int mi = 0; mi < 2; ++mi)
                unpack8(&xcur[(16 * mi + l16) * SXP + q * 8], ah[mi], al[mi]);
            f32x4_t acc[2][2];
#pragma unroll
            for (int ni = 0; ni < 2; ++ni) {
                bf16x8_t bh, bl;
                unpack8(&w1p[(16 * (nb + ni) + l16) * SW1 + q * 8], bh, bl);
#pragma unroll
                for (int mi = 0; mi < 2; ++mi) {
                    f32x4_t a = zero4;
                    a = mfma16(ah[mi], bh, a);
                    a = mfma16(al[mi], bh, a);
                    a = mfma16(ah[mi], bl, a);
                    acc[mi][ni] = a;
                }
            }
#pragma unroll
            for (int mi = 0; mi < 2; ++mi)
#pragma unroll
                for (int ni = 0; ni < 2; ++ni)
#pragma unroll
                    for (int i = 0; i < 4; ++i)
                        h1p[(16 * mi + 4 * q + i) * SH + 16 * (nb + ni) + l16] =
                            pack_split(fmaxf(acc[mi][ni][i], 0.f));
        }
        __syncthreads();   // B1

        // ---- phase 2 (+ gather t+1 into other xgp buffer) ----
        {
            // issue gather loads early (latency hidden under P2 compute)
            float gx[4];
            const int grow = tid >> 3, gg = tid & 7;
            if (t + 1 < TILES_PER_BLOCK) {
                const int base = (row0 + TROWS + grow) * DD;
#pragma unroll
                for (int u = 0; u < 4; ++u)
                    gx[u] = inputs[base + idx_s[4 * gg + u]] * v_s[4 * gg + u];
            }

            f32x4_t acc[2][2] = {{zero4, zero4}, {zero4, zero4}};
#pragma unroll
            for (int ks = 0; ks < 4; ++ks) {
#pragma unroll
                for (int mi = 0; mi < 2; ++mi) {
                    bf16x8_t ah, al;
                    unpack8(&h1p[(16 * mi + l16) * SH + ks * 32 + q * 8], ah, al);
#pragma unroll
                    for (int ni = 0; ni < 2; ++ni) {
                        f32x4_t a = acc[mi][ni];
                        a = mfma16(ah, b2h[ni][ks], a);
                        a = mfma16(al, b2h[ni][ks], a);
                        a = mfma16(ah, b2l[ni][ks], a);
                        acc[mi][ni] = a;
                    }
                }
            }
            if (t + 1 < TILES_PER_BLOCK) {
                uint4 px;
                px.x = pack_split(gx[0]); px.y = pack_split(gx[1]);
                px.z = pack_split(gx[2]); px.w = pack_split(gx[3]);
                *(uint4*)&xgp[(t + 1) & 1][grow * SXP + 4 * gg] = px;
            }
#pragma unroll
            for (int mi = 0; mi < 2; ++mi)
#pragma unroll
                for (int ni = 0; ni < 2; ++ni)
#pragma unroll
                    for (int i = 0; i < 4; ++i)
                        h2p[(16 * mi + 4 * q + i) * SH + 16 * (nb + ni) + l16] =
                            pack_split(fmaxf(acc[mi][ni][i], 0.f));
        }
        __syncthreads();   // B2

        // ---- phase 3 + in-register epilogue ----
        {
            f32x4_t acc[2] = {zero4, zero4};
#pragma unroll
            for (int ks = 0; ks < 4; ++ks) {
#pragma unroll
                for (int mi = 0; mi < 2; ++mi) {
                    bf16x8_t ah, al;
                    unpack8(&h2p[(16 * mi + l16) * SH + ks * 32 + q * 8], ah, al);
                    f32x4_t a = acc[mi];
                    a = mfma16(ah, boh[ks], a);
                    a = mfma16(al, boh[ks], a);
                    a = mfma16(ah, bol[ks], a);
                    acc[mi] = a;
                }
            }
            // acc[mi][i]: row = 16*mi + 4*q + i, col = 16*wave + l16.
            // even l16 -> shift(j), odd l16 -> log_s(j), j = 8*wave + (l16>>1).
            const int p  = lane & 1;
            const int j  = 8 * wave + (l16 >> 1);
            const float vj = v_s[j];
            float part[4];
#pragma unroll
            for (int i = 0; i < 4; ++i) {
                float v = p ? acc[0][i] : acc[1][i];
                float o = __shfl_xor(v, 1, 64);
                const float sh = p ? o : acc[0][i];
                const float ls = p ? acc[1][i] : o;
                const u32 px = xcur[(16 * p + 4 * q + i) * SXP + j];
                const float x = unsplit(px);
                const float uu = (x - sh) * __expf(-ls);
                part[i] = (-0.5f * uu * uu - 0.91893853320467266954f - ls) * vj;
            }
#pragma unroll
            for (int m = 2; m <= 8; m <<= 1)
#pragma unroll
                for (int i = 0; i < 4; ++i)
                    part[i] += __shfl_xor(part[i], m, 64);
            if ((l16 >> 1) == 0) {
#pragma unroll
                for (int i = 0; i < 4; ++i)
                    red[(16 * p + 4 * q + i) * 4 + wave] = part[i];
            }
        }
        __syncthreads();   // B3

        // ---- cross-wave reduce + store (wave 0 only; others proceed to next P1) ----
        if (tid < TROWS) {
            float4 rv = *(const float4*)&red[tid * 4];
            out[(row0 + tid) * RR + r] = rv.x + rv.y + rv.z + rv.w;
        }
    }
}

extern "C" void kernel_launch(void* const* d_in, const int* in_sizes, int n_in,
                              void* d_out, int out_size, void* d_ws, size_t ws_size,
                              hipStream_t stream)
{
    const float* inputs = (const float*)d_in[0];
    const float* W1     = (const float*)d_in[1];
    const float* W2     = (const float*)d_in[2];
    const float* Wout   = (const float*)d_in[3];
    const int*   idx    = (const int*)d_in[4];
    const int*   valid  = (const int*)d_in[5];
    const int*   M1     = (const int*)d_in[6];
    const int*   M2     = (const int*)d_in[7];
    const int*   Mout   = (const int*)d_in[8];
    float*       out    = (float*)d_out;

    hipLaunchKernelGGL(made_flow_r5, dim3(RR * BLOCKS_PER_R), dim3(256), 0, stream,
                       inputs, W1, W2, Wout, idx, valid, M1, M2, Mout, out);
}

// Round 6
// 159.304 us; speedup vs baseline: 1.5626x; 1.0100x over previous
//
#include <hip/hip_runtime.h>
#include <math.h>

// AutoregressiveFlowLayer MI355X — round 6.
// R5 post-mortem: 88us; VALU 47%, LDS ~50% (+223 conflict-cyc/wave-tile), MFMA 20%
// => ~35-40% serialization idle from 3 barriers/tile at 8 waves/CU. Occupancy is
// register-locked (92 VGPR + 96 weight-frag regs => 2 waves/SIMD); evicting weights
// to LDS re-adds R2/R3's traffic. So: cut barriers, not chase occupancy.
// R6:
//  (1) 2 barriers/tile (was 3). Hazard proof: h1 WAR (P2-read -> B2 -> next-P1-write),
//      h2 WAR (P3-read -> B1(t+1) -> next-P2-write), red (epi writes in [B2,B1'],
//      deferred out-store reads in [B1',B2'］). B3 deleted; out-store of tile t-1
//      happens right after B1(t); tail store after final barrier.
//  (2) W1 B-frags in registers too (+16 regs, staged via the same conflict-free
//      scratch rounds) — w1p LDS plane (18.4 KB) and its per-tile reads/unpacks gone.
//      LDS ~44 KB, regs ~200/wave (2 waves/SIMD: 400<=512 OK).
//  Weights MUST stage via LDS scratch (R4 lesson: direct global->reg frags spill).

#define RR 32
#define DD 1024
#define HH 128
#define OO 64
#define TROWS 32
#define TILES_PER_BLOCK 16
#define BLOCKS_PER_R 16

#define SH  132   // packed h row stride (dwords): stores 2-way banks (free), reads balanced
#define SXP 36    // packed xg row stride (dwords)
#define SSC 132   // scratch stride (dwords)

typedef short bf16x8_t __attribute__((ext_vector_type(8)));
typedef float f32x4_t __attribute__((ext_vector_type(4)));
typedef unsigned short u16;
typedef unsigned int u32;

__device__ __forceinline__ u16 bf16_rne(float x) {
    u32 u = __float_as_uint(x);
    u += 0x7FFFu + ((u >> 16) & 1u);
    return (u16)(u >> 16);
}
__device__ __forceinline__ float bf16_tof(u16 h) {
    return __uint_as_float(((u32)h) << 16);
}
__device__ __forceinline__ u32 pack_split(float v) {
    u16 h = bf16_rne(v);
    u16 l = bf16_rne(v - bf16_tof(h));
    return (u32)h | ((u32)l << 16);
}
// packed dword: hi bf16 in bits 0..15, lo-correction bf16 in bits 16..31
__device__ __forceinline__ float unsplit(u32 p) {
    return __uint_as_float(p << 16) + __uint_as_float(p & 0xFFFF0000u);
}
// 8 packed dwords -> hi frag + lo frag
__device__ __forceinline__ void unpack8(const u32* p, bf16x8_t& hi, bf16x8_t& lo) {
    uint4 a = *reinterpret_cast<const uint4*>(p);
    uint4 b = *reinterpret_cast<const uint4*>(p + 4);
    union { u32 u[4]; bf16x8_t v; } H, L;
    H.u[0] = __builtin_amdgcn_perm(a.y, a.x, 0x05040100u);
    H.u[1] = __builtin_amdgcn_perm(a.w, a.z, 0x05040100u);
    H.u[2] = __builtin_amdgcn_perm(b.y, b.x, 0x05040100u);
    H.u[3] = __builtin_amdgcn_perm(b.w, b.z, 0x05040100u);
    L.u[0] = __builtin_amdgcn_perm(a.y, a.x, 0x07060302u);
    L.u[1] = __builtin_amdgcn_perm(a.w, a.z, 0x07060302u);
    L.u[2] = __builtin_amdgcn_perm(b.y, b.x, 0x07060302u);
    L.u[3] = __builtin_amdgcn_perm(b.w, b.z, 0x07060302u);
    hi = H.v; lo = L.v;
}
__device__ __forceinline__ f32x4_t mfma16(bf16x8_t a, bf16x8_t b, f32x4_t c) {
    return __builtin_amdgcn_mfma_f32_16x16x32_bf16(a, b, c, 0, 0, 0);
}

// Stage a [K x 32] slice (row-major src, leading dim ldc, col offset c0) into
// packed-dword [col][k] LDS (stride sd), conflict-free (4x4 in-register transpose,
// uint4 writes). Threads with kb*4 >= K idle.
__device__ __forceinline__ void stage_block(const float* __restrict__ W,
                                            const int* __restrict__ M,
                                            int ldc, int c0, int K, u32* dst, int sd,
                                            int tid)
{
    const int kb = tid >> 3;
    const int cb = tid & 7;
    if (kb * 4 >= K) return;
    const int k0 = kb * 4;
    float e[4][4];
#pragma unroll
    for (int i = 0; i < 4; ++i) {
        const int o = ((k0 + i) * ldc + c0 + 4 * cb) >> 2;
        float4 w = ((const float4*)W)[o];
        int4   m = ((const int4*)M)[o];
        e[i][0] = m.x ? w.x : 0.f; e[i][1] = m.y ? w.y : 0.f;
        e[i][2] = m.z ? w.z : 0.f; e[i][3] = m.w ? w.w : 0.f;
    }
#pragma unroll
    for (int j = 0; j < 4; ++j) {
        uint4 p;
        p.x = pack_split(e[0][j]); p.y = pack_split(e[1][j]);
        p.z = pack_split(e[2][j]); p.w = pack_split(e[3][j]);
        *(uint4*)&dst[(4 * cb + j) * sd + k0] = p;
    }
}

__global__ __launch_bounds__(256, 2)
void made_flow_r6(const float* __restrict__ inputs,
                  const float* __restrict__ W1,
                  const float* __restrict__ W2,
                  const float* __restrict__ Wout,
                  const int* __restrict__ idx,
                  const int* __restrict__ valid,
                  const int* __restrict__ M1,
                  const int* __restrict__ M2,
                  const int* __restrict__ Mout,
                  float* __restrict__ out)
{
    __shared__ __align__(16) u32 regA[TROWS * SH];      // h1 packed | preamble scratch
    __shared__ __align__(16) u32 regB[TROWS * SH];      // h2 packed
    __shared__ __align__(16) u32 xgp[2][TROWS * SXP];   // packed xg, double-buffered
    __shared__ float red[TROWS * 4];
    __shared__ int   idx_s[RR];
    __shared__ float v_s[RR];

    u32* const h1p = regA;
    u32* const scr = regA;
    u32* const h2p = regB;

    const int tid  = threadIdx.x;
    const int r    = blockIdx.x / BLOCKS_PER_R;
    const int rb   = blockIdx.x % BLOCKS_PER_R;
    const int lane = tid & 63;
    const int wave = tid >> 6;
    const int q    = lane >> 4;
    const int l16  = lane & 15;
    const int nb   = 2 * wave;

    if (tid < RR) {
        idx_s[tid] = idx[r * RR + tid];
        v_s[tid]   = valid[r * RR + tid] ? 1.f : 0.f;
    }

    // ---- stage all weights -> per-wave register frags via LDS scratch ----
    bf16x8_t b1h[2], b1l[2];        // W1: cols 16*(nb+ni)+l16, K=32
    bf16x8_t b2h[2][4], b2l[2][4];  // W2: cols 16*(nb+ni)+l16, ks blocks
    bf16x8_t boh[4],    bol[4];     // Wout: cols 16*wave+l16
    {
        const float* W1r = W1 + r * RR * HH;   const int* M1r = M1 + r * RR * HH;
        const float* W2r = W2 + r * HH * HH;   const int* M2r = M2 + r * HH * HH;
        const float* Wor = Wout + r * HH * OO; const int* Mor = Mout + r * HH * OO;
        for (int c = 0; c < 4; ++c) {
            __syncthreads();
            stage_block(W2r, M2r, HH, 32 * c, HH, scr, SSC, tid);
            __syncthreads();
            if (wave == c) {
#pragma unroll
                for (int ni = 0; ni < 2; ++ni)
#pragma unroll
                    for (int ks = 0; ks < 4; ++ks)
                        unpack8(&scr[(16 * ni + l16) * SSC + ks * 32 + q * 8],
                                b2h[ni][ks], b2l[ni][ks]);
            }
        }
        for (int c = 0; c < 2; ++c) {
            __syncthreads();
            stage_block(Wor, Mor, OO, 32 * c, HH, scr, SSC, tid);
            __syncthreads();
            if ((wave >> 1) == c) {
                const int nl = wave & 1;
#pragma unroll
                for (int ks = 0; ks < 4; ++ks)
                    unpack8(&scr[(16 * nl + l16) * SSC + ks * 32 + q * 8],
                            boh[ks], bol[ks]);
            }
        }
        for (int c = 0; c < 4; ++c) {
            __syncthreads();
            stage_block(W1r, M1r, HH, 32 * c, RR, scr, SSC, tid);  // K=32
            __syncthreads();
            if (wave == c) {
#pragma unroll
                for (int ni = 0; ni < 2; ++ni)
                    unpack8(&scr[(16 * ni + l16) * SSC + q * 8], b1h[ni], b1l[ni]);
            }
        }
    }
    __syncthreads();

    // ---- prologue gather -> xgp[0] ----
    {
        const int row  = tid >> 3;
        const int g    = tid & 7;
        const int base = (rb * TILES_PER_BLOCK * TROWS + row) * DD;
        uint4 px;
        px.x = pack_split(inputs[base + idx_s[4 * g + 0]] * v_s[4 * g + 0]);
        px.y = pack_split(inputs[base + idx_s[4 * g + 1]] * v_s[4 * g + 1]);
        px.z = pack_split(inputs[base + idx_s[4 * g + 2]] * v_s[4 * g + 2]);
        px.w = pack_split(inputs[base + idx_s[4 * g + 3]] * v_s[4 * g + 3]);
        *(uint4*)&xgp[0][row * SXP + 4 * g] = px;
    }
    __syncthreads();

    const f32x4_t zero4 = {0.f, 0.f, 0.f, 0.f};

    for (int t = 0; t < TILES_PER_BLOCK; ++t) {
        const int row0 = (rb * TILES_PER_BLOCK + t) * TROWS;
        const u32* xcur = xgp[t & 1];

        // ---- phase 1: h1 = relu(xg @ W1m)  M=32 N=128 K=32 (B in regs) ----
        {
            bf16x8_t ah[2], al[2];
#pragma unroll
            for (int mi = 0; mi < 2; ++mi)
                unpack8(&xcur[(16 * mi + l16) * SXP + q * 8], ah[mi], al[mi]);
            f32x4_t acc[2][2];
#pragma unroll
            for (int ni = 0; ni < 2; ++ni)
#pragma unroll
                for (int mi = 0; mi < 2; ++mi) {
                    f32x4_t a = zero4;
                    a = mfma16(ah[mi], b1h[ni], a);
                    a = mfma16(al[mi], b1h[ni], a);
                    a = mfma16(ah[mi], b1l[ni], a);
                    acc[mi][ni] = a;
                }
#pragma unroll
            for (int mi = 0; mi < 2; ++mi)
#pragma unroll
                for (int ni = 0; ni < 2; ++ni)
#pragma unroll
                    for (int i = 0; i < 4; ++i)
                        h1p[(16 * mi + 4 * q + i) * SH + 16 * (nb + ni) + l16] =
                            pack_split(fmaxf(acc[mi][ni][i], 0.f));
        }
        __syncthreads();   // B1

        // ---- deferred out-store of tile t-1 (red written before B2(t-1)..B1(t)) ----
        if (t > 0 && tid < TROWS) {
            float4 rv = *(const float4*)&red[tid * 4];
            out[(row0 - TROWS + tid) * RR + r] = rv.x + rv.y + rv.z + rv.w;
        }

        // ---- phase 2 (+ gather t+1 into other xgp buffer) ----
        {
            float gx[4];
            const int grow = tid >> 3, gg = tid & 7;
            if (t + 1 < TILES_PER_BLOCK) {
                const int base = (row0 + TROWS + grow) * DD;
#pragma unroll
                for (int u = 0; u < 4; ++u)
                    gx[u] = inputs[base + idx_s[4 * gg + u]] * v_s[4 * gg + u];
            }

            f32x4_t acc[2][2] = {{zero4, zero4}, {zero4, zero4}};
#pragma unroll
            for (int ks = 0; ks < 4; ++ks) {
#pragma unroll
                for (int mi = 0; mi < 2; ++mi) {
                    bf16x8_t ah, al;
                    unpack8(&h1p[(16 * mi + l16) * SH + ks * 32 + q * 8], ah, al);
#pragma unroll
                    for (int ni = 0; ni < 2; ++ni) {
                        f32x4_t a = acc[mi][ni];
                        a = mfma16(ah, b2h[ni][ks], a);
                        a = mfma16(al, b2h[ni][ks], a);
                        a = mfma16(ah, b2l[ni][ks], a);
                        acc[mi][ni] = a;
                    }
                }
            }
            if (t + 1 < TILES_PER_BLOCK) {
                uint4 px;
                px.x = pack_split(gx[0]); px.y = pack_split(gx[1]);
                px.z = pack_split(gx[2]); px.w = pack_split(gx[3]);
                *(uint4*)&xgp[(t + 1) & 1][grow * SXP + 4 * gg] = px;
            }
#pragma unroll
            for (int mi = 0; mi < 2; ++mi)
#pragma unroll
                for (int ni = 0; ni < 2; ++ni)
#pragma unroll
                    for (int i = 0; i < 4; ++i)
                        h2p[(16 * mi + 4 * q + i) * SH + 16 * (nb + ni) + l16] =
                            pack_split(fmaxf(acc[mi][ni][i], 0.f));
        }
        __syncthreads();   // B2

        // ---- phase 3 + in-register epilogue (no trailing barrier) ----
        {
            f32x4_t acc[2] = {zero4, zero4};
#pragma unroll
            for (int ks = 0; ks < 4; ++ks) {
#pragma unroll
                for (int mi = 0; mi < 2; ++mi) {
                    bf16x8_t ah, al;
                    unpack8(&h2p[(16 * mi + l16) * SH + ks * 32 + q * 8], ah, al);
                    f32x4_t a = acc[mi];
                    a = mfma16(ah, boh[ks], a);
                    a = mfma16(al, boh[ks], a);
                    a = mfma16(ah, bol[ks], a);
                    acc[mi] = a;
                }
            }
            // acc[mi][i]: row = 16*mi + 4*q + i, col = 16*wave + l16.
            // even l16 -> shift(j), odd l16 -> log_s(j), j = 8*wave + (l16>>1).
            const int p  = lane & 1;
            const int j  = 8 * wave + (l16 >> 1);
            const float vj = v_s[j];
            float part[4];
#pragma unroll
            for (int i = 0; i < 4; ++i) {
                float v = p ? acc[0][i] : acc[1][i];
                float o = __shfl_xor(v, 1, 64);
                const float sh = p ? o : acc[0][i];
                const float ls = p ? acc[1][i] : o;
                const u32 px = xcur[(16 * p + 4 * q + i) * SXP + j];
                const float x = unsplit(px);
                const float uu = (x - sh) * __expf(-ls);
                part[i] = (-0.5f * uu * uu - 0.91893853320467266954f - ls) * vj;
            }
#pragma unroll
            for (int m = 2; m <= 8; m <<= 1)
#pragma unroll
                for (int i = 0; i < 4; ++i)
                    part[i] += __shfl_xor(part[i], m, 64);
            if ((l16 >> 1) == 0) {
#pragma unroll
                for (int i = 0; i < 4; ++i)
                    red[(16 * p + 4 * q + i) * 4 + wave] = part[i];
            }
        }
        // next iteration's B1 orders red-writes before the deferred read.
    }

    // ---- tail: store last tile's reduction ----
    __syncthreads();
    if (tid < TROWS) {
        float4 rv = *(const float4*)&red[tid * 4];
        out[((rb * TILES_PER_BLOCK + TILES_PER_BLOCK - 1) * TROWS + tid) * RR + r] =
            rv.x + rv.y + rv.z + rv.w;
    }
}

extern "C" void kernel_launch(void* const* d_in, const int* in_sizes, int n_in,
                              void* d_out, int out_size, void* d_ws, size_t ws_size,
                              hipStream_t stream)
{
    const float* inputs = (const float*)d_in[0];
    const float* W1     = (const float*)d_in[1];
    const float* W2     = (const float*)d_in[2];
    const float* Wout   = (const float*)d_in[3];
    const int*   idx    = (const int*)d_in[4];
    const int*   valid  = (const int*)d_in[5];
    const int*   M1     = (const int*)d_in[6];
    const int*   M2     = (const int*)d_in[7];
    const int*   Mout   = (const int*)d_in[8];
    float*       out    = (float*)d_out;

    hipLaunchKernelGGL(made_flow_r6, dim3(RR * BLOCKS_PER_R), dim3(256), 0, stream,
                       inputs, W1, W2, Wout, idx, valid, M1, M2, Mout, out);
}

// Round 7
// 152.844 us; speedup vs baseline: 1.6286x; 1.0423x over previous
//
#include <hip/hip_runtime.h>
#include <math.h>

// AutoregressiveFlowLayer MI355X — round 7.
// R6 post-mortem: JSON 160.9->159.3 (neutral). Model of the 88us kernel: LDS ~49us
// busy, VALU ~41us of which ~144 v_perm unpacks + ~320 pack ops per thread-tile are
// pure format tax; epilogue xgp reads were 4-way bank-conflicted (stride 36 drops
// the p bit from the bank index).
// R7:
//  (1) h1/h2 as SEPARATE hi/lo bf16 u16 planes, stride 136: A-frag reads are direct
//      ds_read_b128 (zero perms); C-stores are ds_write_b16 at 2-addr/bank (free,
//      m136). xg likewise split into planes (P1 A-frags direct).
//  (2) lo = truncated residual ((v-hi)>>16): 2 ops vs 6; adds <=2^-17 rel error
//      (absmax 0.25 -> <=0.5, threshold 1.49).
//  (3) Interval merge, 2 barriers/tile: A = [P2(t) + gather(t+1) + deferred store],
//      B = [P3(t) + P1(t+1) + epilogue(t)]. Hazards: h1 read A(t) / written B(t) -- mid
//      barrier; h1 written B(t) / read A(t+1) -- head barrier; h2 written A / read B;
//      xg[(t+1)&1] written A(t) / read B(t); epi reads xgf[t&1] in B(t), overwritten
//      A(t+1); red written B(t), read A(t+1). All separated by a barrier.
//  (4) xgf stride 33 (odd) -> epilogue reads 2-way/broadcast, conflict-free.
//  Kept: weights staged via LDS scratch into register frags (R4 lesson: direct
//  global->reg spills); 2 blocks/CU register-locked (R5 lesson).

#define RR 32
#define DD 1024
#define HH 128
#define OO 64
#define TROWS 32
#define TILES_PER_BLOCK 16
#define BLOCKS_PER_R 16

#define SHP 136   // u16 stride, h planes: b128 reads balanced, b16 stores 2-way free
#define SXG 40    // u16 stride, xg planes
#define SXF 33    // f32 stride, xgf (odd -> epilogue conflict-free)
#define SSC 132   // u32 scratch stride (preamble weight staging)

typedef short bf16x8_t __attribute__((ext_vector_type(8)));
typedef float f32x4_t __attribute__((ext_vector_type(4)));
typedef unsigned short u16;
typedef unsigned int u32;

__device__ __forceinline__ u16 bf16_rne(float x) {
    u32 u = __float_as_uint(x);
    u += 0x7FFFu + ((u >> 16) & 1u);
    return (u16)(u >> 16);
}
__device__ __forceinline__ float bf16_tof(u16 h) {
    return __uint_as_float(((u32)h) << 16);
}
// truncated lo-residual: bits 16..31 of (v - hi). Error <= 2^-17 relative.
__device__ __forceinline__ u16 lo_trunc(float v, u16 h) {
    return (u16)(__float_as_uint(v - bf16_tof(h)) >> 16);
}
__device__ __forceinline__ u32 pack_split(float v) {
    u16 h = bf16_rne(v);
    return (u32)h | ((u32)lo_trunc(v, h) << 16);
}
// preamble only: 8 packed dwords -> hi/lo frags
__device__ __forceinline__ void unpack8(const u32* p, bf16x8_t& hi, bf16x8_t& lo) {
    uint4 a = *reinterpret_cast<const uint4*>(p);
    uint4 b = *reinterpret_cast<const uint4*>(p + 4);
    union { u32 u[4]; bf16x8_t v; } H, L;
    H.u[0] = __builtin_amdgcn_perm(a.y, a.x, 0x05040100u);
    H.u[1] = __builtin_amdgcn_perm(a.w, a.z, 0x05040100u);
    H.u[2] = __builtin_amdgcn_perm(b.y, b.x, 0x05040100u);
    H.u[3] = __builtin_amdgcn_perm(b.w, b.z, 0x05040100u);
    L.u[0] = __builtin_amdgcn_perm(a.y, a.x, 0x07060302u);
    L.u[1] = __builtin_amdgcn_perm(a.w, a.z, 0x07060302u);
    L.u[2] = __builtin_amdgcn_perm(b.y, b.x, 0x07060302u);
    L.u[3] = __builtin_amdgcn_perm(b.w, b.z, 0x07060302u);
    hi = H.v; lo = L.v;
}
__device__ __forceinline__ f32x4_t mfma16(bf16x8_t a, bf16x8_t b, f32x4_t c) {
    return __builtin_amdgcn_mfma_f32_16x16x32_bf16(a, b, c, 0, 0, 0);
}

// preamble: stage [K x 32] weight slice -> packed-dword [col][k] scratch, conflict-free
__device__ __forceinline__ void stage_block(const float* __restrict__ W,
                                            const int* __restrict__ M,
                                            int ldc, int c0, int K, u32* dst, int sd,
                                            int tid)
{
    const int kb = tid >> 3;
    const int cb = tid & 7;
    if (kb * 4 >= K) return;
    const int k0 = kb * 4;
    float e[4][4];
#pragma unroll
    for (int i = 0; i < 4; ++i) {
        const int o = ((k0 + i) * ldc + c0 + 4 * cb) >> 2;
        float4 w = ((const float4*)W)[o];
        int4   m = ((const int4*)M)[o];
        e[i][0] = m.x ? w.x : 0.f; e[i][1] = m.y ? w.y : 0.f;
        e[i][2] = m.z ? w.z : 0.f; e[i][3] = m.w ? w.w : 0.f;
    }
#pragma unroll
    for (int j = 0; j < 4; ++j) {
        uint4 p;
        p.x = pack_split(e[0][j]); p.y = pack_split(e[1][j]);
        p.z = pack_split(e[2][j]); p.w = pack_split(e[3][j]);
        *(uint4*)&dst[(4 * cb + j) * sd + k0] = p;
    }
}

__global__ __launch_bounds__(256, 2)
void made_flow_r7(const float* __restrict__ inputs,
                  const float* __restrict__ W1,
                  const float* __restrict__ W2,
                  const float* __restrict__ Wout,
                  const int* __restrict__ idx,
                  const int* __restrict__ valid,
                  const int* __restrict__ M1,
                  const int* __restrict__ M2,
                  const int* __restrict__ Mout,
                  float* __restrict__ out)
{
    // regA = h1 hi/lo planes (17408 B), overlaid by u32 preamble scratch (16896 B)
    __shared__ __align__(16) char regA[TROWS * SHP * 2 * 2];
    __shared__ __align__(16) char regB[TROWS * SHP * 2 * 2];
    __shared__ __align__(16) u16  xgh[2][TROWS * SXG];
    __shared__ __align__(16) u16  xgl[2][TROWS * SXG];
    __shared__ float xgf[2][TROWS * SXF];
    __shared__ float red[TROWS * 4];
    __shared__ int   idx_s[RR];
    __shared__ float v_s[RR];

    u16* const h1h = (u16*)regA;
    u16* const h1l = h1h + TROWS * SHP;
    u32* const scr = (u32*)regA;
    u16* const h2h = (u16*)regB;
    u16* const h2l = h2h + TROWS * SHP;

    const int tid  = threadIdx.x;
    const int r    = blockIdx.x / BLOCKS_PER_R;
    const int rb   = blockIdx.x % BLOCKS_PER_R;
    const int lane = tid & 63;
    const int wave = tid >> 6;
    const int q    = lane >> 4;
    const int l16  = lane & 15;
    const int nb   = 2 * wave;

    if (tid < RR) {
        idx_s[tid] = idx[r * RR + tid];
        v_s[tid]   = valid[r * RR + tid] ? 1.f : 0.f;
    }

    // ---- stage all weights -> per-wave register frags via LDS scratch ----
    bf16x8_t b1h[2], b1l[2];
    bf16x8_t b2h[2][4], b2l[2][4];
    bf16x8_t boh[4],    bol[4];
    {
        const float* W1r = W1 + r * RR * HH;   const int* M1r = M1 + r * RR * HH;
        const float* W2r = W2 + r * HH * HH;   const int* M2r = M2 + r * HH * HH;
        const float* Wor = Wout + r * HH * OO; const int* Mor = Mout + r * HH * OO;
        for (int c = 0; c < 4; ++c) {
            __syncthreads();
            stage_block(W2r, M2r, HH, 32 * c, HH, scr, SSC, tid);
            __syncthreads();
            if (wave == c) {
#pragma unroll
                for (int ni = 0; ni < 2; ++ni)
#pragma unroll
                    for (int ks = 0; ks < 4; ++ks)
                        unpack8(&scr[(16 * ni + l16) * SSC + ks * 32 + q * 8],
                                b2h[ni][ks], b2l[ni][ks]);
            }
        }
        for (int c = 0; c < 2; ++c) {
            __syncthreads();
            stage_block(Wor, Mor, OO, 32 * c, HH, scr, SSC, tid);
            __syncthreads();
            if ((wave >> 1) == c) {
                const int nl = wave & 1;
#pragma unroll
                for (int ks = 0; ks < 4; ++ks)
                    unpack8(&scr[(16 * nl + l16) * SSC + ks * 32 + q * 8],
                            boh[ks], bol[ks]);
            }
        }
        for (int c = 0; c < 4; ++c) {
            __syncthreads();
            stage_block(W1r, M1r, HH, 32 * c, RR, scr, SSC, tid);
            __syncthreads();
            if (wave == c) {
#pragma unroll
                for (int ni = 0; ni < 2; ++ni)
                    unpack8(&scr[(16 * ni + l16) * SSC + q * 8], b1h[ni], b1l[ni]);
            }
        }
    }
    __syncthreads();   // scratch reads done before any h1-plane write

    const f32x4_t zero4 = {0.f, 0.f, 0.f, 0.f};
    const int grow = tid >> 3, gg = tid & 7;

    // ---- prologue: gather(0) ----
    {
        const int base = (rb * TILES_PER_BLOCK * TROWS + grow) * DD;
#pragma unroll
        for (int u = 0; u < 4; ++u) {
            const float x = inputs[base + idx_s[4 * gg + u]] * v_s[4 * gg + u];
            const u16 h = bf16_rne(x);
            xgh[0][grow * SXG + 4 * gg + u] = h;
            xgl[0][grow * SXG + 4 * gg + u] = lo_trunc(x, h);
            xgf[0][grow * SXF + 4 * gg + u] = x;
        }
    }
    __syncthreads();

    // ---- prologue: P1(0) ----
    {
        bf16x8_t ah[2], al[2];
#pragma unroll
        for (int mi = 0; mi < 2; ++mi) {
            ah[mi] = *(const bf16x8_t*)&xgh[0][(16 * mi + l16) * SXG + q * 8];
            al[mi] = *(const bf16x8_t*)&xgl[0][(16 * mi + l16) * SXG + q * 8];
        }
        f32x4_t acc[2][2];
#pragma unroll
        for (int ni = 0; ni < 2; ++ni)
#pragma unroll
            for (int mi = 0; mi < 2; ++mi) {
                f32x4_t a = zero4;
                a = mfma16(ah[mi], b1h[ni], a);
                a = mfma16(al[mi], b1h[ni], a);
                a = mfma16(ah[mi], b1l[ni], a);
                acc[mi][ni] = a;
            }
#pragma unroll
        for (int mi = 0; mi < 2; ++mi)
#pragma unroll
            for (int ni = 0; ni < 2; ++ni)
#pragma unroll
                for (int i = 0; i < 4; ++i) {
                    const int o = (16 * mi + 4 * q + i) * SHP + 16 * (nb + ni) + l16;
                    const float v = fmaxf(acc[mi][ni][i], 0.f);
                    const u16 h = bf16_rne(v);
                    h1h[o] = h;
                    h1l[o] = lo_trunc(v, h);
                }
    }

    for (int t = 0; t < TILES_PER_BLOCK; ++t) {
        const int row0 = (rb * TILES_PER_BLOCK + t) * TROWS;
        __syncthreads();   // head barrier (ends B(t-1) / P1(t))

        // ================= interval A: P2(t) + gather(t+1) + deferred store =======
        if (t > 0 && tid < TROWS) {
            float4 rv = *(const float4*)&red[tid * 4];
            out[(row0 - TROWS + tid) * RR + r] = rv.x + rv.y + rv.z + rv.w;
        }
        {
            float gx[4];
            if (t + 1 < TILES_PER_BLOCK) {
                const int base = (row0 + TROWS + grow) * DD;
#pragma unroll
                for (int u = 0; u < 4; ++u)
                    gx[u] = inputs[base + idx_s[4 * gg + u]] * v_s[4 * gg + u];
            }

            f32x4_t acc[2][2] = {{zero4, zero4}, {zero4, zero4}};
#pragma unroll
            for (int ks = 0; ks < 4; ++ks) {
#pragma unroll
                for (int mi = 0; mi < 2; ++mi) {
                    bf16x8_t ah = *(const bf16x8_t*)&h1h[(16 * mi + l16) * SHP + ks * 32 + q * 8];
                    bf16x8_t al = *(const bf16x8_t*)&h1l[(16 * mi + l16) * SHP + ks * 32 + q * 8];
#pragma unroll
                    for (int ni = 0; ni < 2; ++ni) {
                        f32x4_t a = acc[mi][ni];
                        a = mfma16(ah, b2h[ni][ks], a);
                        a = mfma16(al, b2h[ni][ks], a);
                        a = mfma16(ah, b2l[ni][ks], a);
                        acc[mi][ni] = a;
                    }
                }
            }
            if (t + 1 < TILES_PER_BLOCK) {
                const int b = (t + 1) & 1;
                ushort4 gh, gl;
                gh.x = bf16_rne(gx[0]); gl.x = lo_trunc(gx[0], gh.x);
                gh.y = bf16_rne(gx[1]); gl.y = lo_trunc(gx[1], gh.y);
                gh.z = bf16_rne(gx[2]); gl.z = lo_trunc(gx[2], gh.z);
                gh.w = bf16_rne(gx[3]); gl.w = lo_trunc(gx[3], gh.w);
                *(ushort4*)&xgh[b][grow * SXG + 4 * gg] = gh;
                *(ushort4*)&xgl[b][grow * SXG + 4 * gg] = gl;
#pragma unroll
                for (int u = 0; u < 4; ++u)
                    xgf[b][grow * SXF + 4 * gg + u] = gx[u];
            }
#pragma unroll
            for (int mi = 0; mi < 2; ++mi)
#pragma unroll
                for (int ni = 0; ni < 2; ++ni)
#pragma unroll
                    for (int i = 0; i < 4; ++i) {
                        const int o = (16 * mi + 4 * q + i) * SHP + 16 * (nb + ni) + l16;
                        const float v = fmaxf(acc[mi][ni][i], 0.f);
                        const u16 h = bf16_rne(v);
                        h2h[o] = h;
                        h2l[o] = lo_trunc(v, h);
                    }
        }
        __syncthreads();   // mid barrier

        // ============ interval B: P3(t) + P1(t+1) + epilogue(t) ====================
        f32x4_t acc3[2] = {zero4, zero4};
#pragma unroll
        for (int ks = 0; ks < 4; ++ks) {
#pragma unroll
            for (int mi = 0; mi < 2; ++mi) {
                bf16x8_t ah = *(const bf16x8_t*)&h2h[(16 * mi + l16) * SHP + ks * 32 + q * 8];
                bf16x8_t al = *(const bf16x8_t*)&h2l[(16 * mi + l16) * SHP + ks * 32 + q * 8];
                f32x4_t a = acc3[mi];
                a = mfma16(ah, boh[ks], a);
                a = mfma16(al, boh[ks], a);
                a = mfma16(ah, bol[ks], a);
                acc3[mi] = a;
            }
        }

        if (t + 1 < TILES_PER_BLOCK) {   // P1(t+1), independent of acc3/epilogue
            const int b = (t + 1) & 1;
            bf16x8_t ah[2], al[2];
#pragma unroll
            for (int mi = 0; mi < 2; ++mi) {
                ah[mi] = *(const bf16x8_t*)&xgh[b][(16 * mi + l16) * SXG + q * 8];
                al[mi] = *(const bf16x8_t*)&xgl[b][(16 * mi + l16) * SXG + q * 8];
            }
            f32x4_t a1[2][2];
#pragma unroll
            for (int ni = 0; ni < 2; ++ni)
#pragma unroll
                for (int mi = 0; mi < 2; ++mi) {
                    f32x4_t a = zero4;
                    a = mfma16(ah[mi], b1h[ni], a);
                    a = mfma16(al[mi], b1h[ni], a);
                    a = mfma16(ah[mi], b1l[ni], a);
                    a1[mi][ni] = a;
                }
#pragma unroll
            for (int mi = 0; mi < 2; ++mi)
#pragma unroll
                for (int ni = 0; ni < 2; ++ni)
#pragma unroll
                    for (int i = 0; i < 4; ++i) {
                        const int o = (16 * mi + 4 * q + i) * SHP + 16 * (nb + ni) + l16;
                        const float v = fmaxf(a1[mi][ni][i], 0.f);
                        const u16 h = bf16_rne(v);
                        h1h[o] = h;
                        h1l[o] = lo_trunc(v, h);
                    }
        }

        {   // epilogue(t): acc3[mi][i] -> row 16*mi+4*q+i, col 16*wave+l16
            const int p  = lane & 1;
            const int j  = 8 * wave + (l16 >> 1);
            const float vj = v_s[j];
            float part[4];
#pragma unroll
            for (int i = 0; i < 4; ++i) {
                float v = p ? acc3[0][i] : acc3[1][i];
                float o = __shfl_xor(v, 1, 64);
                const float sh = p ? o : acc3[0][i];
                const float ls = p ? acc3[1][i] : o;
                const float x  = xgf[t & 1][(16 * p + 4 * q + i) * SXF + j];
                const float uu = (x - sh) * __expf(-ls);
                part[i] = (-0.5f * uu * uu - 0.91893853320467266954f - ls) * vj;
            }
#pragma unroll
            for (int m = 2; m <= 8; m <<= 1)
#pragma unroll
                for (int i = 0; i < 4; ++i)
                    part[i] += __shfl_xor(part[i], m, 64);
            if ((l16 >> 1) == 0) {
#pragma unroll
                for (int i = 0; i < 4; ++i)
                    red[(16 * p + 4 * q + i) * 4 + wave] = part[i];
            }
        }
    }

    // ---- tail: store last tile's reduction ----
    __syncthreads();
    if (tid < TROWS) {
        float4 rv = *(const float4*)&red[tid * 4];
        out[((rb * TILES_PER_BLOCK + TILES_PER_BLOCK - 1) * TROWS + tid) * RR + r] =
            rv.x + rv.y + rv.z + rv.w;
    }
}

extern "C" void kernel_launch(void* const* d_in, const int* in_sizes, int n_in,
                              void* d_out, int out_size, void* d_ws, size_t ws_size,
                              hipStream_t stream)
{
    const float* inputs = (const float*)d_in[0];
    const float* W1     = (const float*)d_in[1];
    const float* W2     = (const float*)d_in[2];
    const float* Wout   = (const float*)d_in[3];
    const int*   idx    = (const int*)d_in[4];
    const int*   valid  = (const int*)d_in[5];
    const int*   M1     = (const int*)d_in[6];
    const int*   M2     = (const int*)d_in[7];
    const int*   Mout   = (const int*)d_in[8];
    float*       out    = (float*)d_out;

    hipLaunchKernelGGL(made_flow_r7, dim3(RR * BLOCKS_PER_R), dim3(256), 0, stream,
                       inputs, W1, W2, Wout, idx, valid, M1, M2, Mout, out);
}